// Round 4
// baseline (3166.508 us; speedup 1.0000x reference)
//
#include <hip/hip_runtime.h>
#include <math.h>

typedef unsigned short u16;
typedef unsigned int u32;
typedef __attribute__((ext_vector_type(8))) short s16x8;
typedef __attribute__((ext_vector_type(4))) float f32x4;
typedef __attribute__((ext_vector_type(4))) u16 u16x4;

#define B_ 2
#define T_ 2048
#define D_ 1024
#define H_ 16
#define HD_ 64
#define FF_ 4096
#define L_ 8

__device__ __forceinline__ u16 f2b(float f) {
  u32 u = __builtin_bit_cast(u32, f);
  u += 0x7fffu + ((u >> 16) & 1u);
  return (u16)(u >> 16);
}
__device__ __forceinline__ float b2f(u16 h) {
  u32 u = ((u32)h) << 16;
  return __builtin_bit_cast(float, u);
}

__device__ __forceinline__ void load_lds16(const u16* g, u16* l) {
  __builtin_amdgcn_global_load_lds(
      (const __attribute__((address_space(1))) u32*)g,
      (__attribute__((address_space(3))) u32*)l, 16, 0, 0);
}

// ---------------------------------------------------------------------------
// Weight conversion kernels (per-layer slices)
// ---------------------------------------------------------------------------
// W: [3D, D] f32 slice for one layer; conv: [3D] f32 slice. out bf16.
__global__ __launch_bounds__(256) void fold_qkv_kernel(
    const float* __restrict__ W, const float* __restrict__ conv, u16* __restrict__ out) {
  size_t idx = ((size_t)blockIdx.x * 256 + threadIdx.x) * 4;
  size_t row = idx >> 10;  // / D_  (0..3*D_-1)
  float scale = conv[row];
  f32x4 v = *(const f32x4*)&W[idx];
  u16x4 h;
  h.x = f2b(v.x * scale); h.y = f2b(v.y * scale);
  h.z = f2b(v.z * scale); h.w = f2b(v.w * scale);
  *(u16x4*)&out[idx] = h;
}

__global__ __launch_bounds__(256) void cast_kernel(
    const float* __restrict__ in, u16* __restrict__ out) {
  size_t idx = ((size_t)blockIdx.x * 256 + threadIdx.x) * 4;
  f32x4 v = *(const f32x4*)&in[idx];
  u16x4 h;
  h.x = f2b(v.x); h.y = f2b(v.y); h.z = f2b(v.z); h.w = f2b(v.w);
  *(u16x4*)&out[idx] = h;
}

__global__ __launch_bounds__(256) void posadd_kernel(
    const float* __restrict__ q, const float* __restrict__ pos,
    float* __restrict__ xf, u16* __restrict__ xb) {
  size_t idx = ((size_t)blockIdx.x * 256 + threadIdx.x) * 4;
  size_t td = idx & ((size_t)T_ * D_ - 1);  // T*D is power of two
  f32x4 a = *(const f32x4*)&q[idx];
  f32x4 p = *(const f32x4*)&pos[td];
  f32x4 v = a + p;
  *(f32x4*)&xf[idx] = v;
  u16x4 h;
  h.x = f2b(v.x); h.y = f2b(v.y); h.z = f2b(v.z); h.w = f2b(v.w);
  *(u16x4*)&xb[idx] = h;
}

// ---------------------------------------------------------------------------
// GEMM: C[M,N] = A[M,K](bf16) * Bt[N,K](bf16)^T    (m97 structure)
// EPI 0: Cf = acc (f32)
// EPI 1: o = resid + acc; Cf = o; Cb = bf16(o)
// EPI 2: Cb = bf16(gelu(acc))
// EPI 3: Cb = bf16(acc)
// ---------------------------------------------------------------------------
template <int EPI>
__global__ __launch_bounds__(256, 2) void gemm_bt(
    const u16* __restrict__ A, const u16* __restrict__ Bt,
    float* __restrict__ Cf, u16* __restrict__ Cb,
    const float* __restrict__ resid, int M, int N, int K) {
  __shared__ u16 As[128 * 32];
  __shared__ u16 Bs[128 * 32];
  const int tid = threadIdx.x;
  const int lane = tid & 63;
  const int w = tid >> 6;
  const int wr = w >> 1, wc = w & 1;
  const size_t row0 = (size_t)blockIdx.y * 128;
  const size_t col0 = (size_t)blockIdx.x * 128;

  const u16* Ag = A + row0 * K;
  const u16* Bg = Bt + col0 * K;

  f32x4 zero = {0.f, 0.f, 0.f, 0.f};
  f32x4 acc[4][4];
#pragma unroll
  for (int m = 0; m < 4; ++m)
#pragma unroll
    for (int n = 0; n < 4; ++n) acc[m][n] = zero;

  const int chunk0 = w * 2, chunk1 = w * 2 + 1;
  const int e0 = chunk0 * 512 + lane * 8;
  const int e1 = chunk1 * 512 + lane * 8;
  const int r0 = e0 >> 5, c0 = e0 & 31;
  const int r1 = e1 >> 5, c1 = e1 & 31;

  const int fr = lane & 15;
  const int koff = (lane >> 4) * 8;

  for (int k0 = 0; k0 < K; k0 += 32) {
    __syncthreads();
    load_lds16(Ag + (size_t)r0 * K + k0 + c0, &As[chunk0 * 512]);
    load_lds16(Ag + (size_t)r1 * K + k0 + c1, &As[chunk1 * 512]);
    load_lds16(Bg + (size_t)r0 * K + k0 + c0, &Bs[chunk0 * 512]);
    load_lds16(Bg + (size_t)r1 * K + k0 + c1, &Bs[chunk1 * 512]);
    __syncthreads();

    s16x8 a[4], b[4];
#pragma unroll
    for (int m = 0; m < 4; ++m)
      a[m] = *(const s16x8*)&As[(wr * 64 + m * 16 + fr) * 32 + koff];
#pragma unroll
    for (int n = 0; n < 4; ++n)
      b[n] = *(const s16x8*)&Bs[(wc * 64 + n * 16 + fr) * 32 + koff];
#pragma unroll
    for (int m = 0; m < 4; ++m)
#pragma unroll
      for (int n = 0; n < 4; ++n)
        acc[m][n] = __builtin_amdgcn_mfma_f32_16x16x32_bf16(a[m], b[n], acc[m][n], 0, 0, 0);
  }

  const int rq = (lane >> 4) * 4;
#pragma unroll
  for (int m = 0; m < 4; ++m) {
#pragma unroll
    for (int n = 0; n < 4; ++n) {
      size_t col = col0 + wc * 64 + n * 16 + fr;
#pragma unroll
      for (int r = 0; r < 4; ++r) {
        size_t row = row0 + wr * 64 + m * 16 + rq + r;
        size_t idx = row * (size_t)N + col;
        float v = acc[m][n][r];
        if (EPI == 0) {
          Cf[idx] = v;
        } else if (EPI == 1) {
          float o = resid[idx] + v;
          Cf[idx] = o;
          Cb[idx] = f2b(o);
        } else if (EPI == 2) {
          float g = 0.5f * v * (1.0f + erff(v * 0.70710678118654752f));
          Cb[idx] = f2b(g);
        } else {
          Cb[idx] = f2b(v);
        }
      }
    }
  }
}

// ---------------------------------------------------------------------------
// QKV head l2-normalize + scatter to [B*H, T, HD] bf16 (input bf16)
// ---------------------------------------------------------------------------
__global__ __launch_bounds__(256) void qkvnorm_kernel(
    const u16* __restrict__ qkv, u16* __restrict__ qb, u16* __restrict__ kb,
    u16* __restrict__ vb) {
  int gid = blockIdx.x * 4 + (threadIdx.x >> 6);
  int lane = threadIdx.x & 63;
  int h = gid & (H_ - 1);
  int t = (gid >> 4) & (T_ - 1);
  int b = gid >> 15;
  const u16* base = qkv + ((size_t)(b * T_ + t)) * (3 * D_) + h * HD_;
  float qv = b2f(base[lane]);
  float kv = b2f(base[D_ + lane]);
  u16 vv = base[2 * D_ + lane];
  float qs = qv * qv, ks = kv * kv;
#pragma unroll
  for (int off = 1; off < 64; off <<= 1) {
    qs += __shfl_xor(qs, off);
    ks += __shfl_xor(ks, off);
  }
  float qn = qv / fmaxf(sqrtf(qs), 1e-5f);
  float kn = kv / fmaxf(sqrtf(ks), 1e-5f);
  size_t oi = ((size_t)(b * H_ + h) * T_ + t) * HD_ + lane;
  qb[oi] = f2b(qn);
  kb[oi] = f2b(kn);
  vb[oi] = vv;
}

// ---------------------------------------------------------------------------
// Causal flash attention: q-tile 64 rows, k-tiles of 64, 4 waves (16 q rows each)
// ---------------------------------------------------------------------------
__global__ __launch_bounds__(256, 2) void attn_kernel(
    const u16* __restrict__ qg, const u16* __restrict__ kg,
    const u16* __restrict__ vg, u16* __restrict__ y) {
  __shared__ u16 Ks[64 * 72];
  __shared__ u16 Vt[64 * 72];
  __shared__ u16 Ps[4][16 * 72];

  const int tid = threadIdx.x;
  const int lane = tid & 63;
  const int w = tid >> 6;
  const int qt = blockIdx.x;
  const int bh = blockIdx.y;
  const int b = bh >> 4, hh = bh & 15;

  const u16* Q = qg + ((size_t)bh * T_ + qt * 64) * HD_;
  const u16* Kb = kg + (size_t)bh * T_ * HD_;
  const u16* Vb = vg + (size_t)bh * T_ * HD_;

  const int fr = lane & 15;
  const int koff = (lane >> 4) * 8;

  s16x8 qf0 = *(const s16x8*)&Q[(w * 16 + fr) * 64 + koff];
  s16x8 qf1 = *(const s16x8*)&Q[(w * 16 + fr) * 64 + 32 + koff];

  f32x4 zero = {0.f, 0.f, 0.f, 0.f};
  f32x4 o[4];
#pragma unroll
  for (int n = 0; n < 4; ++n) o[n] = zero;
  float mrow[4] = {-1e30f, -1e30f, -1e30f, -1e30f};
  float lrow[4] = {0.f, 0.f, 0.f, 0.f};

  for (int kt = 0; kt <= qt; ++kt) {
    __syncthreads();
    {
      const u16* Kg = Kb + (size_t)kt * 64 * 64;
      const u16* Vg = Vb + (size_t)kt * 64 * 64;
#pragma unroll
      for (int it = 0; it < 2; ++it) {
        int e = (tid * 2 + it) * 8;
        int r = e >> 6, c = e & 63;
        s16x8 kv = *(const s16x8*)&Kg[e];
        *(s16x8*)&Ks[r * 72 + c] = kv;
        s16x8 vv = *(const s16x8*)&Vg[e];
#pragma unroll
        for (int j = 0; j < 8; ++j) Vt[(c + j) * 72 + r] = (u16)vv[j];
      }
    }
    __syncthreads();

    // S = Q K^T  (D layout: row=(lane>>4)*4+r, col=fr)
    f32x4 s[4];
#pragma unroll
    for (int n = 0; n < 4; ++n) {
      s16x8 kf0 = *(const s16x8*)&Ks[(n * 16 + fr) * 72 + koff];
      s16x8 kf1 = *(const s16x8*)&Ks[(n * 16 + fr) * 72 + 32 + koff];
      f32x4 z = zero;
      z = __builtin_amdgcn_mfma_f32_16x16x32_bf16(qf0, kf0, z, 0, 0, 0);
      z = __builtin_amdgcn_mfma_f32_16x16x32_bf16(qf1, kf1, z, 0, 0, 0);
      s[n] = z;
    }

    const int grow_base = qt * 64 + w * 16 + (lane >> 4) * 4;
    const int gcol_base = kt * 64 + fr;
    float p[4][4];
#pragma unroll
    for (int r = 0; r < 4; ++r) {
      float mx = -1e30f;
#pragma unroll
      for (int n = 0; n < 4; ++n) {
        float sv = s[n][r] * 0.125f;
        if (gcol_base + n * 16 > grow_base + r) sv = -1e30f;
        s[n][r] = sv;
        mx = fmaxf(mx, sv);
      }
#pragma unroll
      for (int off = 1; off < 16; off <<= 1) mx = fmaxf(mx, __shfl_xor(mx, off));
      float mnew = fmaxf(mrow[r], mx);
      float sc = __expf(mrow[r] - mnew);
      float rs = 0.f;
#pragma unroll
      for (int n = 0; n < 4; ++n) {
        float pv = __expf(s[n][r] - mnew);
        p[n][r] = pv;
        rs += pv;
      }
#pragma unroll
      for (int off = 1; off < 16; off <<= 1) rs += __shfl_xor(rs, off);
      lrow[r] = lrow[r] * sc + rs;
      mrow[r] = mnew;
#pragma unroll
      for (int n = 0; n < 4; ++n) o[n][r] *= sc;
    }

    // P (D layout) -> LDS -> A layout
    u16* Pw = &Ps[w][0];
#pragma unroll
    for (int n = 0; n < 4; ++n)
#pragma unroll
      for (int r = 0; r < 4; ++r)
        Pw[((lane >> 4) * 4 + r) * 72 + n * 16 + fr] = f2b(p[n][r]);
    asm volatile("s_waitcnt lgkmcnt(0)" ::: "memory");

    s16x8 pa0 = *(const s16x8*)&Pw[fr * 72 + koff];
    s16x8 pa1 = *(const s16x8*)&Pw[fr * 72 + 32 + koff];
#pragma unroll
    for (int n = 0; n < 4; ++n) {
      s16x8 v0 = *(const s16x8*)&Vt[(n * 16 + fr) * 72 + koff];
      s16x8 v1 = *(const s16x8*)&Vt[(n * 16 + fr) * 72 + 32 + koff];
      o[n] = __builtin_amdgcn_mfma_f32_16x16x32_bf16(pa0, v0, o[n], 0, 0, 0);
      o[n] = __builtin_amdgcn_mfma_f32_16x16x32_bf16(pa1, v1, o[n], 0, 0, 0);
    }
  }

#pragma unroll
  for (int n = 0; n < 4; ++n)
#pragma unroll
    for (int r = 0; r < 4; ++r) {
      int grow = qt * 64 + w * 16 + (lane >> 4) * 4 + r;
      float val = o[n][r] / lrow[r];
      y[((size_t)b * T_ + grow) * D_ + hh * 64 + n * 16 + fr] = f2b(val);
    }
}

// ---------------------------------------------------------------------------
// Final LayerNorm
// ---------------------------------------------------------------------------
__global__ __launch_bounds__(256) void ln_kernel(
    const float* __restrict__ x, const float* __restrict__ gamma,
    float* __restrict__ out) {
  int row = blockIdx.x;
  int tid = threadIdx.x;
  const float* xr = x + (size_t)row * D_;
  f32x4 v = *(const f32x4*)&xr[tid * 4];
  float s = v.x + v.y + v.z + v.w;
  float ss = v.x * v.x + v.y * v.y + v.z * v.z + v.w * v.w;
#pragma unroll
  for (int off = 1; off < 64; off <<= 1) {
    s += __shfl_xor(s, off);
    ss += __shfl_xor(ss, off);
  }
  __shared__ float red[8];
  int w = tid >> 6, lane = tid & 63;
  if (lane == 0) {
    red[w] = s;
    red[4 + w] = ss;
  }
  __syncthreads();
  s = red[0] + red[1] + red[2] + red[3];
  ss = red[4] + red[5] + red[6] + red[7];
  float mu = s * (1.f / D_);
  float var = ss * (1.f / D_) - mu * mu;
  float rstd = rsqrtf(var + 1e-5f);
  f32x4 g = *(const f32x4*)&gamma[tid * 4];
  f32x4 o;
  o.x = (v.x - mu) * rstd * g.x;
  o.y = (v.y - mu) * rstd * g.y;
  o.z = (v.z - mu) * rstd * g.z;
  o.w = (v.w - mu) * rstd * g.w;
  *(f32x4*)&out[(size_t)row * D_ + tid * 4] = o;
}

// ---------------------------------------------------------------------------
extern "C" void kernel_launch(void* const* d_in, const int* in_sizes, int n_in,
                              void* d_out, int out_size, void* d_ws, size_t ws_size,
                              hipStream_t stream) {
  (void)in_sizes; (void)n_in; (void)out_size; (void)ws_size;
  const float* q = (const float*)d_in[0];
  const float* pos = (const float*)d_in[1];
  const float* Wqkv = (const float*)d_in[2];
  const float* convw = (const float*)d_in[3];
  const float* projw = (const float*)d_in[4];
  const float* fcw = (const float*)d_in[5];
  const float* mlpw = (const float*)d_in[6];
  const float* gamma = (const float*)d_in[7];
  float* out = (float*)d_out;

  char* ws = (char*)d_ws;
  size_t off = 0;
  auto alloc = [&](size_t bytes) {
    char* p = ws + off;
    off += (bytes + 255) & ~(size_t)255;
    return p;
  };
  // per-layer element counts
  const size_t nWq = (size_t)3 * D_ * D_;   // 3145728
  const size_t nPr = (size_t)D_ * D_;       // 1048576
  const size_t nFc = (size_t)FF_ * D_;      // 4194304
  const size_t nMl = (size_t)D_ * FF_;      // 4194304
  const size_t nX = (size_t)B_ * T_ * D_;   // 4194304
  const size_t nQKV = (size_t)B_ * T_ * 3 * D_;  // 12582912
  const size_t nH = (size_t)B_ * T_ * FF_;       // 16777216

  // total workspace ~118 MB (per-layer weight staging, reused each layer)
  u16* Wqb = (u16*)alloc(nWq * 2);
  u16* Prb = (u16*)alloc(nPr * 2);
  u16* Fcb = (u16*)alloc(nFc * 2);
  u16* Mlb = (u16*)alloc(nMl * 2);
  float* xf = (float*)alloc(nX * 4);
  u16* xb = (u16*)alloc(nX * 2);
  // qkv bf16 output and FC-hidden share one scratch region (disjoint lifetimes)
  size_t shared_bytes = nH * 2 > nQKV * 2 ? nH * 2 : nQKV * 2;
  u16* qkvb = (u16*)alloc(shared_bytes);
  u16* hb = qkvb;
  u16* qb = (u16*)alloc(nX * 2);
  u16* kb = (u16*)alloc(nX * 2);
  u16* vb = (u16*)alloc(nX * 2);
  u16* yb = (u16*)alloc(nX * 2);

  posadd_kernel<<<nX / 1024, 256, 0, stream>>>(q, pos, xf, xb);

  const int M = B_ * T_;  // 4096
  for (int l = 0; l < L_; ++l) {
    // convert this layer's weights (reuses the same buffers every layer;
    // stream order guarantees the previous layer's GEMMs are done)
    fold_qkv_kernel<<<nWq / 1024, 256, 0, stream>>>(
        Wqkv + (size_t)l * nWq, convw + (size_t)l * 3 * D_, Wqb);
    cast_kernel<<<nPr / 1024, 256, 0, stream>>>(projw + (size_t)l * nPr, Prb);
    cast_kernel<<<nFc / 1024, 256, 0, stream>>>(fcw + (size_t)l * nFc, Fcb);
    cast_kernel<<<nMl / 1024, 256, 0, stream>>>(mlpw + (size_t)l * nMl, Mlb);

    gemm_bt<3><<<dim3(3 * D_ / 128, M / 128), 256, 0, stream>>>(
        xb, Wqb, nullptr, qkvb, nullptr, M, 3 * D_, D_);
    qkvnorm_kernel<<<(B_ * T_ * H_) / 4, 256, 0, stream>>>(qkvb, qb, kb, vb);
    attn_kernel<<<dim3(T_ / 64, B_ * H_), 256, 0, stream>>>(qb, kb, vb, yb);
    gemm_bt<1><<<dim3(D_ / 128, M / 128), 256, 0, stream>>>(
        yb, Prb, xf, xb, xf, M, D_, D_);
    gemm_bt<2><<<dim3(FF_ / 128, M / 128), 256, 0, stream>>>(
        xb, Fcb, nullptr, hb, nullptr, M, FF_, D_);
    gemm_bt<1><<<dim3(D_ / 128, M / 128), 256, 0, stream>>>(
        hb, Mlb, xf, xb, xf, M, D_, FF_);
  }
  ln_kernel<<<B_ * T_, 256, 0, stream>>>(xf, gamma, out);
}

// Round 5
// 3005.889 us; speedup vs baseline: 1.0534x; 1.0534x over previous
//
#include <hip/hip_runtime.h>
#include <math.h>

typedef unsigned short u16;
typedef unsigned int u32;
typedef __attribute__((ext_vector_type(8))) short s16x8;
typedef __attribute__((ext_vector_type(4))) float f32x4;
typedef __attribute__((ext_vector_type(4))) u16 u16x4;

#define B_ 2
#define T_ 2048
#define D_ 1024
#define H_ 16
#define HD_ 64
#define FF_ 4096
#define L_ 8

__device__ __forceinline__ u16 f2b(float f) {
  u32 u = __builtin_bit_cast(u32, f);
  u += 0x7fffu + ((u >> 16) & 1u);
  return (u16)(u >> 16);
}
__device__ __forceinline__ float b2f(u16 h) {
  u32 u = ((u32)h) << 16;
  return __builtin_bit_cast(float, u);
}

__device__ __forceinline__ void load_lds16(const u16* g, u16* l) {
  __builtin_amdgcn_global_load_lds(
      (const __attribute__((address_space(1))) u32*)g,
      (__attribute__((address_space(3))) u32*)l, 16, 0, 0);
}

// ---------------------------------------------------------------------------
// Weight conversion kernels (per-layer slices)
// ---------------------------------------------------------------------------
__global__ __launch_bounds__(256) void fold_qkv_kernel(
    const float* __restrict__ W, const float* __restrict__ conv, u16* __restrict__ out) {
  size_t idx = ((size_t)blockIdx.x * 256 + threadIdx.x) * 4;
  size_t row = idx >> 10;  // / D_  (0..3*D_-1)
  float scale = conv[row];
  f32x4 v = *(const f32x4*)&W[idx];
  u16x4 h;
  h.x = f2b(v.x * scale); h.y = f2b(v.y * scale);
  h.z = f2b(v.z * scale); h.w = f2b(v.w * scale);
  *(u16x4*)&out[idx] = h;
}

__global__ __launch_bounds__(256) void cast_kernel(
    const float* __restrict__ in, u16* __restrict__ out) {
  size_t idx = ((size_t)blockIdx.x * 256 + threadIdx.x) * 4;
  f32x4 v = *(const f32x4*)&in[idx];
  u16x4 h;
  h.x = f2b(v.x); h.y = f2b(v.y); h.z = f2b(v.z); h.w = f2b(v.w);
  *(u16x4*)&out[idx] = h;
}

__global__ __launch_bounds__(256) void posadd_kernel(
    const float* __restrict__ q, const float* __restrict__ pos,
    float* __restrict__ xf, u16* __restrict__ xb) {
  size_t idx = ((size_t)blockIdx.x * 256 + threadIdx.x) * 4;
  size_t td = idx & ((size_t)T_ * D_ - 1);  // T*D is power of two
  f32x4 a = *(const f32x4*)&q[idx];
  f32x4 p = *(const f32x4*)&pos[td];
  f32x4 v = a + p;
  *(f32x4*)&xf[idx] = v;
  u16x4 h;
  h.x = f2b(v.x); h.y = f2b(v.y); h.z = f2b(v.z); h.w = f2b(v.w);
  *(u16x4*)&xb[idx] = h;
}

// ---------------------------------------------------------------------------
// GEMM: C[M,N] = A[M,K](bf16) * Bt[N,K](bf16)^T    (m97 structure)
// ---------------------------------------------------------------------------
template <int EPI>
__global__ __launch_bounds__(256, 2) void gemm_bt(
    const u16* __restrict__ A, const u16* __restrict__ Bt,
    float* __restrict__ Cf, u16* __restrict__ Cb,
    const float* __restrict__ resid, int M, int N, int K) {
  __shared__ u16 As[128 * 32];
  __shared__ u16 Bs[128 * 32];
  const int tid = threadIdx.x;
  const int lane = tid & 63;
  const int w = tid >> 6;
  const int wr = w >> 1, wc = w & 1;
  const size_t row0 = (size_t)blockIdx.y * 128;
  const size_t col0 = (size_t)blockIdx.x * 128;

  const u16* Ag = A + row0 * K;
  const u16* Bg = Bt + col0 * K;

  f32x4 zero = {0.f, 0.f, 0.f, 0.f};
  f32x4 acc[4][4];
#pragma unroll
  for (int m = 0; m < 4; ++m)
#pragma unroll
    for (int n = 0; n < 4; ++n) acc[m][n] = zero;

  const int chunk0 = w * 2, chunk1 = w * 2 + 1;
  const int e0 = chunk0 * 512 + lane * 8;
  const int e1 = chunk1 * 512 + lane * 8;
  const int r0 = e0 >> 5, c0 = e0 & 31;
  const int r1 = e1 >> 5, c1 = e1 & 31;

  const int fr = lane & 15;
  const int koff = (lane >> 4) * 8;

  for (int k0 = 0; k0 < K; k0 += 32) {
    __syncthreads();
    load_lds16(Ag + (size_t)r0 * K + k0 + c0, &As[chunk0 * 512]);
    load_lds16(Ag + (size_t)r1 * K + k0 + c1, &As[chunk1 * 512]);
    load_lds16(Bg + (size_t)r0 * K + k0 + c0, &Bs[chunk0 * 512]);
    load_lds16(Bg + (size_t)r1 * K + k0 + c1, &Bs[chunk1 * 512]);
    __syncthreads();

    s16x8 a[4], b[4];
#pragma unroll
    for (int m = 0; m < 4; ++m)
      a[m] = *(const s16x8*)&As[(wr * 64 + m * 16 + fr) * 32 + koff];
#pragma unroll
    for (int n = 0; n < 4; ++n)
      b[n] = *(const s16x8*)&Bs[(wc * 64 + n * 16 + fr) * 32 + koff];
#pragma unroll
    for (int m = 0; m < 4; ++m)
#pragma unroll
      for (int n = 0; n < 4; ++n)
        acc[m][n] = __builtin_amdgcn_mfma_f32_16x16x32_bf16(a[m], b[n], acc[m][n], 0, 0, 0);
  }

  const int rq = (lane >> 4) * 4;
#pragma unroll
  for (int m = 0; m < 4; ++m) {
#pragma unroll
    for (int n = 0; n < 4; ++n) {
      size_t col = col0 + wc * 64 + n * 16 + fr;
#pragma unroll
      for (int r = 0; r < 4; ++r) {
        size_t row = row0 + wr * 64 + m * 16 + rq + r;
        size_t idx = row * (size_t)N + col;
        float v = acc[m][n][r];
        if (EPI == 0) {
          Cf[idx] = v;
        } else if (EPI == 1) {
          float o = resid[idx] + v;
          Cf[idx] = o;
          Cb[idx] = f2b(o);
        } else if (EPI == 2) {
          float g = 0.5f * v * (1.0f + erff(v * 0.70710678118654752f));
          Cb[idx] = f2b(g);
        } else {
          Cb[idx] = f2b(v);
        }
      }
    }
  }
}

// ---------------------------------------------------------------------------
// QKV head l2-normalize + scatter to [B*H, T, HD] bf16 (input bf16)
// ---------------------------------------------------------------------------
__global__ __launch_bounds__(256) void qkvnorm_kernel(
    const u16* __restrict__ qkv, u16* __restrict__ qb, u16* __restrict__ kb,
    u16* __restrict__ vb) {
  int gid = blockIdx.x * 4 + (threadIdx.x >> 6);
  int lane = threadIdx.x & 63;
  int h = gid & (H_ - 1);
  int t = (gid >> 4) & (T_ - 1);
  int b = gid >> 15;
  const u16* base = qkv + ((size_t)(b * T_ + t)) * (3 * D_) + h * HD_;
  float qv = b2f(base[lane]);
  float kv = b2f(base[D_ + lane]);
  u16 vv = base[2 * D_ + lane];
  float qs = qv * qv, ks = kv * kv;
#pragma unroll
  for (int off = 1; off < 64; off <<= 1) {
    qs += __shfl_xor(qs, off);
    ks += __shfl_xor(ks, off);
  }
  float qn = qv / fmaxf(sqrtf(qs), 1e-5f);
  float kn = kv / fmaxf(sqrtf(ks), 1e-5f);
  size_t oi = ((size_t)(b * H_ + h) * T_ + t) * HD_ + lane;
  qb[oi] = f2b(qn);
  kb[oi] = f2b(kn);
  vb[oi] = vv;
}

// ---------------------------------------------------------------------------
// V transpose: [bh][T][HD] -> [bh][HD][T]  (once per layer; kills the per-
// q-tile in-kernel scalar transpose that caused 1.1e7 bank conflicts)
// ---------------------------------------------------------------------------
__global__ __launch_bounds__(256) void vtrans_kernel(
    const u16* __restrict__ vb, u16* __restrict__ vt) {
  __shared__ u16 tile[64 * 72];
  const int bh = blockIdx.y;
  const int t0 = blockIdx.x * 64;
  const int tid = threadIdx.x;
  const u16* src = vb + ((size_t)bh * T_ + t0) * HD_;
#pragma unroll
  for (int it = 0; it < 2; ++it) {
    int e = (tid * 2 + it) * 8;
    int r = e >> 6, c = e & 63;  // r = local t, c = d
    s16x8 v = *(const s16x8*)&src[(size_t)r * HD_ + c];
    *(s16x8*)&tile[r * 72 + c] = v;
  }
  __syncthreads();
#pragma unroll
  for (int it = 0; it < 2; ++it) {
    int e = (tid * 2 + it) * 8;
    int d = e >> 6, c = e & 63;  // d = head dim row, c = local t chunk
    u16 tmp[8];
#pragma unroll
    for (int j = 0; j < 8; ++j) tmp[j] = tile[(c + j) * 72 + d];
    *(s16x8*)&vt[((size_t)bh * HD_ + d) * T_ + t0 + c] = *(const s16x8*)tmp;
  }
}

// ---------------------------------------------------------------------------
// Causal flash attention: q-tile 128 rows, 8 waves (16 q rows each),
// k-tiles of 64. K [bh][T][HD] row-major; V^T [bh][HD][T] precomputed.
// ---------------------------------------------------------------------------
__global__ __launch_bounds__(512) void attn_kernel(
    const u16* __restrict__ qg, const u16* __restrict__ kg,
    const u16* __restrict__ vtg, u16* __restrict__ y) {
  __shared__ u16 Ks[64 * 72];   // [k-row t'][d]
  __shared__ u16 Vt[64 * 72];   // [d][k-row t']
  __shared__ u16 Ps[8][16 * 72];

  const int tid = threadIdx.x;
  const int lane = tid & 63;
  const int w = tid >> 6;       // 0..7
  const int qt = blockIdx.x;    // 0..15
  const int bh = blockIdx.y;
  const int b = bh >> 4, hh = bh & 15;

  const u16* Q = qg + ((size_t)bh * T_ + qt * 128) * HD_;
  const u16* Kb = kg + (size_t)bh * T_ * HD_;
  const u16* Vg = vtg + (size_t)bh * HD_ * T_;

  const int fr = lane & 15;
  const int koff = (lane >> 4) * 8;

  s16x8 qf0 = *(const s16x8*)&Q[(w * 16 + fr) * HD_ + koff];
  s16x8 qf1 = *(const s16x8*)&Q[(w * 16 + fr) * HD_ + 32 + koff];

  f32x4 zero = {0.f, 0.f, 0.f, 0.f};
  f32x4 o[4];
#pragma unroll
  for (int n = 0; n < 4; ++n) o[n] = zero;
  float mrow[4] = {-1e30f, -1e30f, -1e30f, -1e30f};
  float lrow[4] = {0.f, 0.f, 0.f, 0.f};

  // staging indices: 512 threads x 8 u16 = one 64x64 tile
  const int sr = tid >> 3;          // 0..63
  const int sc = (tid & 7) * 8;     // 0..56

  const int ktmax = 2 * qt + 1;
  for (int kt = 0; kt <= ktmax; ++kt) {
    __syncthreads();
    {
      s16x8 kv = *(const s16x8*)&Kb[((size_t)kt * 64 + sr) * HD_ + sc];
      *(s16x8*)&Ks[sr * 72 + sc] = kv;
      s16x8 vv = *(const s16x8*)&Vg[(size_t)sr * T_ + kt * 64 + sc];
      *(s16x8*)&Vt[sr * 72 + sc] = vv;
    }
    __syncthreads();

    // S = Q K^T  (D layout: row=(lane>>4)*4+r, col=n*16+fr)
    f32x4 s[4];
#pragma unroll
    for (int n = 0; n < 4; ++n) {
      s16x8 kf0 = *(const s16x8*)&Ks[(n * 16 + fr) * 72 + koff];
      s16x8 kf1 = *(const s16x8*)&Ks[(n * 16 + fr) * 72 + 32 + koff];
      f32x4 z = zero;
      z = __builtin_amdgcn_mfma_f32_16x16x32_bf16(qf0, kf0, z, 0, 0, 0);
      z = __builtin_amdgcn_mfma_f32_16x16x32_bf16(qf1, kf1, z, 0, 0, 0);
      s[n] = z;
    }

    const int grow_base = qt * 128 + w * 16 + (lane >> 4) * 4;
    const int gcol_base = kt * 64 + fr;
    float p[4][4];
#pragma unroll
    for (int r = 0; r < 4; ++r) {
      float mx = -1e30f;
#pragma unroll
      for (int n = 0; n < 4; ++n) {
        float sv = s[n][r] * 0.125f;
        if (gcol_base + n * 16 > grow_base + r) sv = -1e30f;
        s[n][r] = sv;
        mx = fmaxf(mx, sv);
      }
#pragma unroll
      for (int off = 1; off < 16; off <<= 1) mx = fmaxf(mx, __shfl_xor(mx, off));
      float mnew = fmaxf(mrow[r], mx);
      float sc2 = __expf(mrow[r] - mnew);
      float rs = 0.f;
#pragma unroll
      for (int n = 0; n < 4; ++n) {
        float pv = __expf(s[n][r] - mnew);
        p[n][r] = pv;
        rs += pv;
      }
#pragma unroll
      for (int off = 1; off < 16; off <<= 1) rs += __shfl_xor(rs, off);
      lrow[r] = lrow[r] * sc2 + rs;
      mrow[r] = mnew;
#pragma unroll
      for (int n = 0; n < 4; ++n) o[n][r] *= sc2;
    }

    // P (D layout) -> LDS -> A layout   (wave-local region, lgkm-fenced)
    u16* Pw = &Ps[w][0];
#pragma unroll
    for (int n = 0; n < 4; ++n)
#pragma unroll
      for (int r = 0; r < 4; ++r)
        Pw[((lane >> 4) * 4 + r) * 72 + n * 16 + fr] = f2b(p[n][r]);
    asm volatile("s_waitcnt lgkmcnt(0)" ::: "memory");

    s16x8 pa0 = *(const s16x8*)&Pw[fr * 72 + koff];
    s16x8 pa1 = *(const s16x8*)&Pw[fr * 72 + 32 + koff];
#pragma unroll
    for (int n = 0; n < 4; ++n) {
      s16x8 v0 = *(const s16x8*)&Vt[(n * 16 + fr) * 72 + koff];
      s16x8 v1 = *(const s16x8*)&Vt[(n * 16 + fr) * 72 + 32 + koff];
      o[n] = __builtin_amdgcn_mfma_f32_16x16x32_bf16(pa0, v0, o[n], 0, 0, 0);
      o[n] = __builtin_amdgcn_mfma_f32_16x16x32_bf16(pa1, v1, o[n], 0, 0, 0);
    }
  }

#pragma unroll
  for (int n = 0; n < 4; ++n)
#pragma unroll
    for (int r = 0; r < 4; ++r) {
      int grow = qt * 128 + w * 16 + (lane >> 4) * 4 + r;
      float val = o[n][r] / lrow[r];
      y[((size_t)b * T_ + grow) * D_ + hh * 64 + n * 16 + fr] = f2b(val);
    }
}

// ---------------------------------------------------------------------------
// Final LayerNorm
// ---------------------------------------------------------------------------
__global__ __launch_bounds__(256) void ln_kernel(
    const float* __restrict__ x, const float* __restrict__ gamma,
    float* __restrict__ out) {
  int row = blockIdx.x;
  int tid = threadIdx.x;
  const float* xr = x + (size_t)row * D_;
  f32x4 v = *(const f32x4*)&xr[tid * 4];
  float s = v.x + v.y + v.z + v.w;
  float ss = v.x * v.x + v.y * v.y + v.z * v.z + v.w * v.w;
#pragma unroll
  for (int off = 1; off < 64; off <<= 1) {
    s += __shfl_xor(s, off);
    ss += __shfl_xor(ss, off);
  }
  __shared__ float red[8];
  int w = tid >> 6, lane = tid & 63;
  if (lane == 0) {
    red[w] = s;
    red[4 + w] = ss;
  }
  __syncthreads();
  s = red[0] + red[1] + red[2] + red[3];
  ss = red[4] + red[5] + red[6] + red[7];
  float mu = s * (1.f / D_);
  float var = ss * (1.f / D_) - mu * mu;
  float rstd = rsqrtf(var + 1e-5f);
  f32x4 g = *(const f32x4*)&gamma[tid * 4];
  f32x4 o;
  o.x = (v.x - mu) * rstd * g.x;
  o.y = (v.y - mu) * rstd * g.y;
  o.z = (v.z - mu) * rstd * g.z;
  o.w = (v.w - mu) * rstd * g.w;
  *(f32x4*)&out[(size_t)row * D_ + tid * 4] = o;
}

// ---------------------------------------------------------------------------
extern "C" void kernel_launch(void* const* d_in, const int* in_sizes, int n_in,
                              void* d_out, int out_size, void* d_ws, size_t ws_size,
                              hipStream_t stream) {
  (void)in_sizes; (void)n_in; (void)out_size; (void)ws_size;
  const float* q = (const float*)d_in[0];
  const float* pos = (const float*)d_in[1];
  const float* Wqkv = (const float*)d_in[2];
  const float* convw = (const float*)d_in[3];
  const float* projw = (const float*)d_in[4];
  const float* fcw = (const float*)d_in[5];
  const float* mlpw = (const float*)d_in[6];
  const float* gamma = (const float*)d_in[7];
  float* out = (float*)d_out;

  char* ws = (char*)d_ws;
  size_t off = 0;
  auto alloc = [&](size_t bytes) {
    char* p = ws + off;
    off += (bytes + 255) & ~(size_t)255;
    return p;
  };
  // per-layer element counts
  const size_t nWq = (size_t)3 * D_ * D_;
  const size_t nPr = (size_t)D_ * D_;
  const size_t nFc = (size_t)FF_ * D_;
  const size_t nMl = (size_t)D_ * FF_;
  const size_t nX = (size_t)B_ * T_ * D_;
  const size_t nQKV = (size_t)B_ * T_ * 3 * D_;
  const size_t nH = (size_t)B_ * T_ * FF_;

  u16* Wqb = (u16*)alloc(nWq * 2);
  u16* Prb = (u16*)alloc(nPr * 2);
  u16* Fcb = (u16*)alloc(nFc * 2);
  u16* Mlb = (u16*)alloc(nMl * 2);
  float* xf = (float*)alloc(nX * 4);
  u16* xb = (u16*)alloc(nX * 2);
  size_t shared_bytes = nH * 2 > nQKV * 2 ? nH * 2 : nQKV * 2;
  u16* qkvb = (u16*)alloc(shared_bytes);
  u16* hb = qkvb;
  u16* qb = (u16*)alloc(nX * 2);
  u16* kb = (u16*)alloc(nX * 2);
  u16* vb = (u16*)alloc(nX * 2);
  u16* vtb = (u16*)alloc(nX * 2);
  u16* yb = (u16*)alloc(nX * 2);

  posadd_kernel<<<nX / 1024, 256, 0, stream>>>(q, pos, xf, xb);

  const int M = B_ * T_;  // 4096
  for (int l = 0; l < L_; ++l) {
    fold_qkv_kernel<<<nWq / 1024, 256, 0, stream>>>(
        Wqkv + (size_t)l * nWq, convw + (size_t)l * 3 * D_, Wqb);
    cast_kernel<<<nPr / 1024, 256, 0, stream>>>(projw + (size_t)l * nPr, Prb);
    cast_kernel<<<nFc / 1024, 256, 0, stream>>>(fcw + (size_t)l * nFc, Fcb);
    cast_kernel<<<nMl / 1024, 256, 0, stream>>>(mlpw + (size_t)l * nMl, Mlb);

    gemm_bt<3><<<dim3(3 * D_ / 128, M / 128), 256, 0, stream>>>(
        xb, Wqb, nullptr, qkvb, nullptr, M, 3 * D_, D_);
    qkvnorm_kernel<<<(B_ * T_ * H_) / 4, 256, 0, stream>>>(qkvb, qb, kb, vb);
    vtrans_kernel<<<dim3(T_ / 64, B_ * H_), 256, 0, stream>>>(vb, vtb);
    attn_kernel<<<dim3(T_ / 128, B_ * H_), 512, 0, stream>>>(qb, kb, vtb, yb);
    gemm_bt<1><<<dim3(D_ / 128, M / 128), 256, 0, stream>>>(
        yb, Prb, xf, xb, xf, M, D_, D_);
    gemm_bt<2><<<dim3(FF_ / 128, M / 128), 256, 0, stream>>>(
        xb, Fcb, nullptr, hb, nullptr, M, FF_, D_);
    gemm_bt<1><<<dim3(D_ / 128, M / 128), 256, 0, stream>>>(
        hb, Mlb, xf, xb, xf, M, D_, FF_);
  }
  ln_kernel<<<B_ * T_, 256, 0, stream>>>(xf, gamma, out);
}

// Round 6
// 2736.596 us; speedup vs baseline: 1.1571x; 1.0984x over previous
//
#include <hip/hip_runtime.h>
#include <math.h>

typedef unsigned short u16;
typedef unsigned int u32;
typedef __attribute__((ext_vector_type(8))) short s16x8;
typedef __attribute__((ext_vector_type(4))) float f32x4;
typedef __attribute__((ext_vector_type(4))) u16 u16x4;

#define B_ 2
#define T_ 2048
#define D_ 1024
#define H_ 16
#define HD_ 64
#define FF_ 4096
#define L_ 8

__device__ __forceinline__ u16 f2b(float f) {
  u32 u = __builtin_bit_cast(u32, f);
  u += 0x7fffu + ((u >> 16) & 1u);
  return (u16)(u >> 16);
}
__device__ __forceinline__ float b2f(u16 h) {
  u32 u = ((u32)h) << 16;
  return __builtin_bit_cast(float, u);
}

__device__ __forceinline__ void load_lds16(const u16* g, u16* l) {
  __builtin_amdgcn_global_load_lds(
      (const __attribute__((address_space(1))) u32*)g,
      (__attribute__((address_space(3))) u32*)l, 16, 0, 0);
}

// ---------------------------------------------------------------------------
// Weight conversion kernels (per-layer slices)
// ---------------------------------------------------------------------------
__global__ __launch_bounds__(256) void fold_qkv_kernel(
    const float* __restrict__ W, const float* __restrict__ conv, u16* __restrict__ out) {
  size_t idx = ((size_t)blockIdx.x * 256 + threadIdx.x) * 4;
  size_t row = idx >> 10;  // / D_
  float scale = conv[row];
  f32x4 v = *(const f32x4*)&W[idx];
  u16x4 h;
  h.x = f2b(v.x * scale); h.y = f2b(v.y * scale);
  h.z = f2b(v.z * scale); h.w = f2b(v.w * scale);
  *(u16x4*)&out[idx] = h;
}

__global__ __launch_bounds__(256) void cast_kernel(
    const float* __restrict__ in, u16* __restrict__ out) {
  size_t idx = ((size_t)blockIdx.x * 256 + threadIdx.x) * 4;
  f32x4 v = *(const f32x4*)&in[idx];
  u16x4 h;
  h.x = f2b(v.x); h.y = f2b(v.y); h.z = f2b(v.z); h.w = f2b(v.w);
  *(u16x4*)&out[idx] = h;
}

__global__ __launch_bounds__(256) void posadd_kernel(
    const float* __restrict__ q, const float* __restrict__ pos,
    float* __restrict__ xf, u16* __restrict__ xb) {
  size_t idx = ((size_t)blockIdx.x * 256 + threadIdx.x) * 4;
  size_t td = idx & ((size_t)T_ * D_ - 1);
  f32x4 a = *(const f32x4*)&q[idx];
  f32x4 p = *(const f32x4*)&pos[td];
  f32x4 v = a + p;
  *(f32x4*)&xf[idx] = v;
  u16x4 h;
  h.x = f2b(v.x); h.y = f2b(v.y); h.z = f2b(v.z); h.w = f2b(v.w);
  *(u16x4*)&xb[idx] = h;
}

// ---------------------------------------------------------------------------
// GEMM: C[M,N] = A[M,K](bf16) * Bt[N,K](bf16)^T
// m97 structure, BK=64, XOR-swizzled LDS (col8 ^= row&7):
//   - global_load_lds dest stays LINEAR (HW requirement)
//   - global SOURCE col8 pre-swizzled; READ applies same XOR (involution)
//   - gives 8 bank-groups x 4 banks on fragment ds_read_b128 (optimal)
// ---------------------------------------------------------------------------
template <int EPI>
__global__ __launch_bounds__(256, 2) void gemm_bt(
    const u16* __restrict__ A, const u16* __restrict__ Bt,
    float* __restrict__ Cf, u16* __restrict__ Cb,
    const float* __restrict__ resid, int M, int N, int K) {
  __shared__ u16 As[128 * 64];
  __shared__ u16 Bs[128 * 64];
  const int tid = threadIdx.x;
  const int lane = tid & 63;
  const int w = tid >> 6;
  const int wr = w >> 1, wc = w & 1;
  const size_t row0 = (size_t)blockIdx.y * 128;
  const size_t col0 = (size_t)blockIdx.x * 128;

  const u16* Ag = A + row0 * K;
  const u16* Bg = Bt + col0 * K;

  f32x4 zero = {0.f, 0.f, 0.f, 0.f};
  f32x4 acc[4][4];
#pragma unroll
  for (int m = 0; m < 4; ++m)
#pragma unroll
    for (int n = 0; n < 4; ++n) acc[m][n] = zero;

  // staging geometry: round i covers rows i*32 + (tid>>3), col8 = tid&7
  const int srow = tid >> 3;          // 0..31 (plus i*32)
  const int scol8 = tid & 7;          // dest col8 (linear)
  const int fr = lane & 15;
  const int g = lane >> 4;            // 0..3
  const int koff = g * 8;

  for (int k0 = 0; k0 < K; k0 += 64) {
    __syncthreads();
#pragma unroll
    for (int i = 0; i < 4; ++i) {
      int rd = i * 32 + srow;
      int sc8 = scol8 ^ (rd & 7);     // pre-swizzled global source
      load_lds16(Ag + (size_t)rd * K + k0 + sc8 * 8, &As[i * 2048 + w * 512]);
      load_lds16(Bg + (size_t)rd * K + k0 + sc8 * 8, &Bs[i * 2048 + w * 512]);
    }
    __syncthreads();

#pragma unroll
    for (int kk = 0; kk < 2; ++kk) {
      s16x8 a[4], b[4];
#pragma unroll
      for (int m = 0; m < 4; ++m) {
        int ra = wr * 64 + m * 16 + fr;
        int c8 = (kk * 4 + g) ^ (fr & 7);   // read-side XOR (row&7 == fr&7)
        a[m] = *(const s16x8*)&As[ra * 64 + c8 * 8];
      }
#pragma unroll
      for (int n = 0; n < 4; ++n) {
        int rb = wc * 64 + n * 16 + fr;
        int c8 = (kk * 4 + g) ^ (fr & 7);
        b[n] = *(const s16x8*)&Bs[rb * 64 + c8 * 8];
      }
#pragma unroll
      for (int m = 0; m < 4; ++m)
#pragma unroll
        for (int n = 0; n < 4; ++n)
          acc[m][n] = __builtin_amdgcn_mfma_f32_16x16x32_bf16(a[m], b[n], acc[m][n], 0, 0, 0);
    }
  }

  const int rq = g * 4;
#pragma unroll
  for (int m = 0; m < 4; ++m) {
#pragma unroll
    for (int n = 0; n < 4; ++n) {
      size_t col = col0 + wc * 64 + n * 16 + fr;
#pragma unroll
      for (int r = 0; r < 4; ++r) {
        size_t row = row0 + wr * 64 + m * 16 + rq + r;
        size_t idx = row * (size_t)N + col;
        float v = acc[m][n][r];
        if (EPI == 0) {
          Cf[idx] = v;
        } else if (EPI == 1) {
          float o = resid[idx] + v;
          Cf[idx] = o;
          Cb[idx] = f2b(o);
        } else if (EPI == 2) {
          float ge = 0.5f * v * (1.0f + erff(v * 0.70710678118654752f));
          Cb[idx] = f2b(ge);
        } else {
          Cb[idx] = f2b(v);
        }
      }
    }
  }
}

// ---------------------------------------------------------------------------
// QKV head l2-normalize + scatter to [B*H, T, HD] bf16 (input bf16)
// ---------------------------------------------------------------------------
__global__ __launch_bounds__(256) void qkvnorm_kernel(
    const u16* __restrict__ qkv, u16* __restrict__ qb, u16* __restrict__ kb,
    u16* __restrict__ vb) {
  int gid = blockIdx.x * 4 + (threadIdx.x >> 6);
  int lane = threadIdx.x & 63;
  int h = gid & (H_ - 1);
  int t = (gid >> 4) & (T_ - 1);
  int b = gid >> 15;
  const u16* base = qkv + ((size_t)(b * T_ + t)) * (3 * D_) + h * HD_;
  float qv = b2f(base[lane]);
  float kv = b2f(base[D_ + lane]);
  u16 vv = base[2 * D_ + lane];
  float qs = qv * qv, ks = kv * kv;
#pragma unroll
  for (int off = 1; off < 64; off <<= 1) {
    qs += __shfl_xor(qs, off);
    ks += __shfl_xor(ks, off);
  }
  float qn = qv / fmaxf(sqrtf(qs), 1e-5f);
  float kn = kv / fmaxf(sqrtf(ks), 1e-5f);
  size_t oi = ((size_t)(b * H_ + h) * T_ + t) * HD_ + lane;
  qb[oi] = f2b(qn);
  kb[oi] = f2b(kn);
  vb[oi] = vv;
}

// ---------------------------------------------------------------------------
// V transpose: [bh][T][HD] -> [bh][HD][T]  (once per layer)
// ---------------------------------------------------------------------------
__global__ __launch_bounds__(256) void vtrans_kernel(
    const u16* __restrict__ vb, u16* __restrict__ vt) {
  __shared__ u16 tile[64 * 72];
  const int bh = blockIdx.y;
  const int t0 = blockIdx.x * 64;
  const int tid = threadIdx.x;
  const u16* src = vb + ((size_t)bh * T_ + t0) * HD_;
#pragma unroll
  for (int it = 0; it < 2; ++it) {
    int e = (tid * 2 + it) * 8;
    int r = e >> 6, c = e & 63;
    s16x8 v = *(const s16x8*)&src[(size_t)r * HD_ + c];
    *(s16x8*)&tile[r * 72 + c] = v;
  }
  __syncthreads();
#pragma unroll
  for (int it = 0; it < 2; ++it) {
    int e = (tid * 2 + it) * 8;
    int d = e >> 6, c = e & 63;
    u16 tmp[8];
#pragma unroll
    for (int j = 0; j < 8; ++j) tmp[j] = tile[(c + j) * 72 + d];
    *(s16x8*)&vt[((size_t)bh * HD_ + d) * T_ + t0 + c] = *(const s16x8*)tmp;
  }
}

// ---------------------------------------------------------------------------
// Causal flash attention: q-tile 128 rows, 8 waves, k-tiles of 64.
// T14 prefetch: next tile's K/V global loads issued into registers right
// after staging, landing under the compute phase. Heavy q-tiles first (LPT).
// ---------------------------------------------------------------------------
__global__ __launch_bounds__(512) void attn_kernel(
    const u16* __restrict__ qg, const u16* __restrict__ kg,
    const u16* __restrict__ vtg, u16* __restrict__ y) {
  __shared__ u16 Ks[64 * 72];
  __shared__ u16 Vt[64 * 72];
  __shared__ u16 Ps[8][16 * 72];

  const int tid = threadIdx.x;
  const int lane = tid & 63;
  const int w = tid >> 6;
  const int qt = (T_ / 128 - 1) - blockIdx.x;  // heavy-first
  const int bh = blockIdx.y;
  const int b = bh >> 4, hh = bh & 15;

  const u16* Q = qg + ((size_t)bh * T_ + qt * 128) * HD_;
  const u16* Kb = kg + (size_t)bh * T_ * HD_;
  const u16* Vg = vtg + (size_t)bh * HD_ * T_;

  const int fr = lane & 15;
  const int koff = (lane >> 4) * 8;

  s16x8 qf0 = *(const s16x8*)&Q[(w * 16 + fr) * HD_ + koff];
  s16x8 qf1 = *(const s16x8*)&Q[(w * 16 + fr) * HD_ + 32 + koff];

  f32x4 zero = {0.f, 0.f, 0.f, 0.f};
  f32x4 o[4];
#pragma unroll
  for (int n = 0; n < 4; ++n) o[n] = zero;
  float mrow[4] = {-1e30f, -1e30f, -1e30f, -1e30f};
  float lrow[4] = {0.f, 0.f, 0.f, 0.f};

  const int sr = tid >> 3;
  const int sc = (tid & 7) * 8;
  const int ktmax = 2 * qt + 1;

  // prefetch tile 0
  s16x8 kv = *(const s16x8*)&Kb[((size_t)sr) * HD_ + sc];
  s16x8 vv = *(const s16x8*)&Vg[(size_t)sr * T_ + sc];

  for (int kt = 0; kt <= ktmax; ++kt) {
    __syncthreads();
    *(s16x8*)&Ks[sr * 72 + sc] = kv;
    *(s16x8*)&Vt[sr * 72 + sc] = vv;
    __syncthreads();
    if (kt < ktmax) {  // issue next tile's loads; land under compute below
      kv = *(const s16x8*)&Kb[((size_t)(kt + 1) * 64 + sr) * HD_ + sc];
      vv = *(const s16x8*)&Vg[(size_t)sr * T_ + (kt + 1) * 64 + sc];
    }

    // S = Q K^T  (D layout: row=(lane>>4)*4+r, col=n*16+fr)
    f32x4 s[4];
#pragma unroll
    for (int n = 0; n < 4; ++n) {
      s16x8 kf0 = *(const s16x8*)&Ks[(n * 16 + fr) * 72 + koff];
      s16x8 kf1 = *(const s16x8*)&Ks[(n * 16 + fr) * 72 + 32 + koff];
      f32x4 z = zero;
      z = __builtin_amdgcn_mfma_f32_16x16x32_bf16(qf0, kf0, z, 0, 0, 0);
      z = __builtin_amdgcn_mfma_f32_16x16x32_bf16(qf1, kf1, z, 0, 0, 0);
      s[n] = z;
    }

    const int grow_base = qt * 128 + w * 16 + (lane >> 4) * 4;
    const int gcol_base = kt * 64 + fr;
    float p[4][4];
#pragma unroll
    for (int r = 0; r < 4; ++r) {
      float mx = -1e30f;
#pragma unroll
      for (int n = 0; n < 4; ++n) {
        float sv = s[n][r] * 0.125f;
        if (gcol_base + n * 16 > grow_base + r) sv = -1e30f;
        s[n][r] = sv;
        mx = fmaxf(mx, sv);
      }
#pragma unroll
      for (int off = 1; off < 16; off <<= 1) mx = fmaxf(mx, __shfl_xor(mx, off));
      float mnew = fmaxf(mrow[r], mx);
      float sc2 = __expf(mrow[r] - mnew);
      float rs = 0.f;
#pragma unroll
      for (int n = 0; n < 4; ++n) {
        float pv = __expf(s[n][r] - mnew);
        p[n][r] = pv;
        rs += pv;
      }
#pragma unroll
      for (int off = 1; off < 16; off <<= 1) rs += __shfl_xor(rs, off);
      lrow[r] = lrow[r] * sc2 + rs;
      mrow[r] = mnew;
#pragma unroll
      for (int n = 0; n < 4; ++n) o[n][r] *= sc2;
    }

    // P (D layout) -> LDS -> A layout   (wave-local region, lgkm-fenced)
    u16* Pw = &Ps[w][0];
#pragma unroll
    for (int n = 0; n < 4; ++n)
#pragma unroll
      for (int r = 0; r < 4; ++r)
        Pw[((lane >> 4) * 4 + r) * 72 + n * 16 + fr] = f2b(p[n][r]);
    asm volatile("s_waitcnt lgkmcnt(0)" ::: "memory");

    s16x8 pa0 = *(const s16x8*)&Pw[fr * 72 + koff];
    s16x8 pa1 = *(const s16x8*)&Pw[fr * 72 + 32 + koff];
#pragma unroll
    for (int n = 0; n < 4; ++n) {
      s16x8 v0 = *(const s16x8*)&Vt[(n * 16 + fr) * 72 + koff];
      s16x8 v1 = *(const s16x8*)&Vt[(n * 16 + fr) * 72 + 32 + koff];
      o[n] = __builtin_amdgcn_mfma_f32_16x16x32_bf16(pa0, v0, o[n], 0, 0, 0);
      o[n] = __builtin_amdgcn_mfma_f32_16x16x32_bf16(pa1, v1, o[n], 0, 0, 0);
    }
  }

#pragma unroll
  for (int n = 0; n < 4; ++n)
#pragma unroll
    for (int r = 0; r < 4; ++r) {
      int grow = qt * 128 + w * 16 + (lane >> 4) * 4 + r;
      float val = o[n][r] / lrow[r];
      y[((size_t)b * T_ + grow) * D_ + hh * 64 + n * 16 + fr] = f2b(val);
    }
}

// ---------------------------------------------------------------------------
// Final LayerNorm
// ---------------------------------------------------------------------------
__global__ __launch_bounds__(256) void ln_kernel(
    const float* __restrict__ x, const float* __restrict__ gamma,
    float* __restrict__ out) {
  int row = blockIdx.x;
  int tid = threadIdx.x;
  const float* xr = x + (size_t)row * D_;
  f32x4 v = *(const f32x4*)&xr[tid * 4];
  float s = v.x + v.y + v.z + v.w;
  float ss = v.x * v.x + v.y * v.y + v.z * v.z + v.w * v.w;
#pragma unroll
  for (int off = 1; off < 64; off <<= 1) {
    s += __shfl_xor(s, off);
    ss += __shfl_xor(ss, off);
  }
  __shared__ float red[8];
  int w = tid >> 6, lane = tid & 63;
  if (lane == 0) {
    red[w] = s;
    red[4 + w] = ss;
  }
  __syncthreads();
  s = red[0] + red[1] + red[2] + red[3];
  ss = red[4] + red[5] + red[6] + red[7];
  float mu = s * (1.f / D_);
  float var = ss * (1.f / D_) - mu * mu;
  float rstd = rsqrtf(var + 1e-5f);
  f32x4 g = *(const f32x4*)&gamma[tid * 4];
  f32x4 o;
  o.x = (v.x - mu) * rstd * g.x;
  o.y = (v.y - mu) * rstd * g.y;
  o.z = (v.z - mu) * rstd * g.z;
  o.w = (v.w - mu) * rstd * g.w;
  *(f32x4*)&out[(size_t)row * D_ + tid * 4] = o;
}

// ---------------------------------------------------------------------------
extern "C" void kernel_launch(void* const* d_in, const int* in_sizes, int n_in,
                              void* d_out, int out_size, void* d_ws, size_t ws_size,
                              hipStream_t stream) {
  (void)in_sizes; (void)n_in; (void)out_size; (void)ws_size;
  const float* q = (const float*)d_in[0];
  const float* pos = (const float*)d_in[1];
  const float* Wqkv = (const float*)d_in[2];
  const float* convw = (const float*)d_in[3];
  const float* projw = (const float*)d_in[4];
  const float* fcw = (const float*)d_in[5];
  const float* mlpw = (const float*)d_in[6];
  const float* gamma = (const float*)d_in[7];
  float* out = (float*)d_out;

  char* ws = (char*)d_ws;
  size_t off = 0;
  auto alloc = [&](size_t bytes) {
    char* p = ws + off;
    off += (bytes + 255) & ~(size_t)255;
    return p;
  };
  const size_t nWq = (size_t)3 * D_ * D_;
  const size_t nPr = (size_t)D_ * D_;
  const size_t nFc = (size_t)FF_ * D_;
  const size_t nMl = (size_t)D_ * FF_;
  const size_t nX = (size_t)B_ * T_ * D_;
  const size_t nQKV = (size_t)B_ * T_ * 3 * D_;
  const size_t nH = (size_t)B_ * T_ * FF_;

  u16* Wqb = (u16*)alloc(nWq * 2);
  u16* Prb = (u16*)alloc(nPr * 2);
  u16* Fcb = (u16*)alloc(nFc * 2);
  u16* Mlb = (u16*)alloc(nMl * 2);
  float* xf = (float*)alloc(nX * 4);
  u16* xb = (u16*)alloc(nX * 2);
  size_t shared_bytes = nH * 2 > nQKV * 2 ? nH * 2 : nQKV * 2;
  u16* qkvb = (u16*)alloc(shared_bytes);
  u16* hb = qkvb;
  u16* qb = (u16*)alloc(nX * 2);
  u16* kb = (u16*)alloc(nX * 2);
  u16* vb = (u16*)alloc(nX * 2);
  u16* vtb = (u16*)alloc(nX * 2);
  u16* yb = (u16*)alloc(nX * 2);

  posadd_kernel<<<nX / 1024, 256, 0, stream>>>(q, pos, xf, xb);

  const int M = B_ * T_;  // 4096
  for (int l = 0; l < L_; ++l) {
    fold_qkv_kernel<<<nWq / 1024, 256, 0, stream>>>(
        Wqkv + (size_t)l * nWq, convw + (size_t)l * 3 * D_, Wqb);
    cast_kernel<<<nPr / 1024, 256, 0, stream>>>(projw + (size_t)l * nPr, Prb);
    cast_kernel<<<nFc / 1024, 256, 0, stream>>>(fcw + (size_t)l * nFc, Fcb);
    cast_kernel<<<nMl / 1024, 256, 0, stream>>>(mlpw + (size_t)l * nMl, Mlb);

    gemm_bt<3><<<dim3(3 * D_ / 128, M / 128), 256, 0, stream>>>(
        xb, Wqb, nullptr, qkvb, nullptr, M, 3 * D_, D_);
    qkvnorm_kernel<<<(B_ * T_ * H_) / 4, 256, 0, stream>>>(qkvb, qb, kb, vb);
    vtrans_kernel<<<dim3(T_ / 64, B_ * H_), 256, 0, stream>>>(vb, vtb);
    attn_kernel<<<dim3(T_ / 128, B_ * H_), 512, 0, stream>>>(qb, kb, vtb, yb);
    gemm_bt<1><<<dim3(D_ / 128, M / 128), 256, 0, stream>>>(
        yb, Prb, xf, xb, xf, M, D_, D_);
    gemm_bt<2><<<dim3(FF_ / 128, M / 128), 256, 0, stream>>>(
        xb, Fcb, nullptr, hb, nullptr, M, FF_, D_);
    gemm_bt<1><<<dim3(D_ / 128, M / 128), 256, 0, stream>>>(
        hb, Mlb, xf, xb, xf, M, D_, FF_);
  }
  ln_kernel<<<B_ * T_, 256, 0, stream>>>(xf, gamma, out);
}